// Round 1
// baseline (162.858 us; speedup 1.0000x reference)
//
#include <hip/hip_runtime.h>
#include <hip/hip_bf16.h>

// Embedding gather: out[i, :] = weight[idx[i], :]
// idx: [8*4096] int32, weight: [50257, 512] fp32, out: [8*4096, 512] fp32.
// One thread per float4 of output (EMBED=512 -> 128 float4 per row).

#define EMBED_F4 128          // 512 floats / 4
#define N_IDX    (8 * 4096)   // 32768 indices
#define TOTAL_F4 (N_IDX * EMBED_F4)

__global__ __launch_bounds__(256) void Embedding_60327110640045_kernel(
    const int* __restrict__ idx,
    const float4* __restrict__ weight,   // [50257 * 128] float4
    float4* __restrict__ out)            // [32768 * 128] float4
{
    int tid = blockIdx.x * blockDim.x + threadIdx.x;
    if (tid >= TOTAL_F4) return;
    int row = tid >> 7;        // which index
    int col = tid & 127;       // which float4 within the row
    int w_row = idx[row];
    out[tid] = weight[(long long)w_row * EMBED_F4 + col];
}

extern "C" void kernel_launch(void* const* d_in, const int* in_sizes, int n_in,
                              void* d_out, int out_size, void* d_ws, size_t ws_size,
                              hipStream_t stream) {
    const int*    idx    = (const int*)d_in[0];
    const float4* weight = (const float4*)d_in[1];
    float4*       out    = (float4*)d_out;

    const int block = 256;
    const int grid  = (TOTAL_F4 + block - 1) / block;  // 16384 blocks
    Embedding_60327110640045_kernel<<<grid, block, 0, stream>>>(idx, weight, out);
}